// Round 1
// 840.398 us; speedup vs baseline: 1.0017x; 1.0017x over previous
//
#include <hip/hip_runtime.h>
#include <hip/hip_bf16.h>
#include <stdint.h>

#define N_NODES 16384
#define IN_SIZE 4096
#define EMB 500
#define EMBP 512
#define NEDGE 524288

typedef __attribute__((ext_vector_type(8))) short bf16x8_t;
typedef __attribute__((ext_vector_type(4))) float f32x4_t;

__device__ __forceinline__ unsigned short f2bf(float f) {
    union { float f; unsigned u; } v; v.f = f;
    unsigned r = v.u + 0x7FFFu + ((v.u >> 16) & 1u);
    return (unsigned short)(r >> 16);
}
__device__ __forceinline__ float bf2f(unsigned short h) {
    union { float f; unsigned u; } v; v.u = ((unsigned)h) << 16;
    return v.f;
}

// async global->LDS, 16B per lane. LDS dest is wave-uniform base + lane*16.
__device__ __forceinline__ void gload_lds16(const void* g, void* l) {
    __builtin_amdgcn_global_load_lds(
        (__attribute__((address_space(1))) void*)(g),
        (__attribute__((address_space(3))) void*)(l),
        16, 0, 0);
}

__global__ void zero_i32(int* p, int n) {
    int i = blockIdx.x * 256 + threadIdx.x;
    if (i < n) p[i] = 0;
}

// edge_index delivered by harness as int32 [2, E]: row = ei[e], col = ei[E + e]
__global__ void hist_k(const int* __restrict__ ei, int* __restrict__ deg, int* __restrict__ coldeg) {
    int e = blockIdx.x * 256 + threadIdx.x;
    int r = ei[e];
    int c = ei[NEDGE + e];
    atomicAdd(&deg[r], 1);
    atomicAdd(&coldeg[c], 1);
}

__global__ void dinv_k(const int* __restrict__ deg, float* __restrict__ dinv) {
    int i = blockIdx.x * 256 + threadIdx.x;
    int d = deg[i];
    dinv[i] = d > 0 ? rsqrtf((float)d) : 0.f;
}

// exclusive scan of coldeg[16384] -> colptr[16385]; cursor = copy of colptr[0:16384]
__global__ void scan_k(const int* __restrict__ coldeg, int* __restrict__ colptr, int* __restrict__ cursor) {
    __shared__ int part[256];
    int t = threadIdx.x;
    int base = t * 64;
    int s = 0;
    for (int i = 0; i < 64; ++i) s += coldeg[base + i];
    part[t] = s;
    __syncthreads();
    for (int off = 1; off < 256; off <<= 1) {
        int v = part[t];
        int add = (t >= off) ? part[t - off] : 0;
        __syncthreads();
        part[t] = v + add;
        __syncthreads();
    }
    int ex = (t > 0) ? part[t - 1] : 0;
    for (int i = 0; i < 64; ++i) {
        colptr[base + i] = ex;
        cursor[base + i] = ex;
        ex += coldeg[base + i];
    }
    if (t == 255) colptr[N_NODES] = ex;
}

__global__ void fill_k(const int* __restrict__ ei, const float* __restrict__ dinv,
                       int* __restrict__ cursor, int* __restrict__ csr_src, float* __restrict__ csr_nrm) {
    int e = blockIdx.x * 256 + threadIdx.x;
    int r = ei[e];
    int c = ei[NEDGE + e];
    int pos = atomicAdd(&cursor[c], 1);
    csr_src[pos] = r;
    csr_nrm[pos] = dinv[r] * dinv[c];
}

// wenc [500,4096] fp32 -> [512,4096] bf16, pad rows zero
__global__ void cast_wenc_k(const float* __restrict__ w, unsigned short* __restrict__ wb) {
    int i = blockIdx.x * 256 + threadIdx.x;
    int row = i >> 12;
    wb[i] = (row < EMB) ? f2bf(w[i]) : (unsigned short)0;
}

// wdec [4096,500] fp32 -> [4096,512] bf16, pad cols zero
__global__ void cast_wdec_k(const float* __restrict__ w, unsigned short* __restrict__ wb) {
    int i = blockIdx.x * 256 + threadIdx.x;
    int row = i >> 9;
    int col = i & 511;
    wb[i] = (col < EMB) ? f2bf(w[row * EMB + col]) : (unsigned short)0;
}

// C[M,N] = act(A[M,K] @ B[N,K]^T + bias). 128x128 tile, BK=32, 4 waves of 64x64.
// m97 structure: LINEAR LDS tiles (no pad) + global_load_lds width-16 staging for
// all bf16 operands. Bank conflicts on ds_read are accepted (T2 is NULL at the
// 2-barrier structure; m97 hit 874 TF with the same ~1.7e7 conflict count).
// AF32: A is fp32, converted to bf16 during manual LDS staging (encode path).
// SIG: sigmoid + bf16 store (pad cols >= NL stored as 0); else fp32 store.
template<bool AF32, bool SIG>
__global__ __launch_bounds__(256, 2) void gemm_bt(
    const void* __restrict__ Av, const unsigned short* __restrict__ B,
    const float* __restrict__ bias, void* __restrict__ Cout,
    int M, int N, int K, int NL)
{
    constexpr int BM = 128, BN = 128, BK = 32;
    __shared__ unsigned short As[BM * BK];
    __shared__ unsigned short Bs[BN * BK];
    int tid = threadIdx.x;
    int lane = tid & 63;
    int wave = tid >> 6;
    int rowA0 = blockIdx.x * BM;
    int colB0 = blockIdx.y * BN;
    int wm = (wave >> 1) * 64;
    int wn = (wave & 1) * 64;

    f32x4_t acc[4][4];
    #pragma unroll
    for (int i = 0; i < 4; ++i)
        #pragma unroll
        for (int j = 0; j < 4; ++j)
            acc[i][j] = (f32x4_t){0.f, 0.f, 0.f, 0.f};

    int fr = lane & 15;
    int kb = (lane >> 4) * 8;

    // async-staging geometry: wave w owns 32 rows [32w, 32w+32), 2 instrs of 16 rows.
    // lane l covers row (l>>2), 16B chunk (l&3) within its 16-row slab.
    int sRow = wave * 32 + (lane >> 2);
    int sCol = (lane & 3) * 8;
    const unsigned short* Ab = (const unsigned short*)Av;
    unsigned short* AsW = &As[(wave * 32) * BK];
    unsigned short* BsW = &Bs[(wave * 32) * BK];

    // AF32 manual-staging geometry: thread covers 4B-rows x 4 cols, 4 row-reps.
    int cr = tid >> 3;
    int ck = (tid & 7) * 4;

    for (int k0 = 0; k0 < K; k0 += BK) {
        __syncthreads();
        if constexpr (AF32) {
            const float* A = (const float*)Av;
            #pragma unroll
            for (int rep = 0; rep < 4; ++rep) {
                float4 v = *(const float4*)(A + (size_t)(rowA0 + cr + rep * 32) * K + k0 + ck);
                uint2 pv;
                pv.x = (unsigned)f2bf(v.x) | ((unsigned)f2bf(v.y) << 16);
                pv.y = (unsigned)f2bf(v.z) | ((unsigned)f2bf(v.w) << 16);
                *(uint2*)&As[(cr + rep * 32) * BK + ck] = pv;
            }
        } else {
            #pragma unroll
            for (int t = 0; t < 2; ++t)
                gload_lds16(Ab + (size_t)(rowA0 + sRow + t * 16) * K + k0 + sCol,
                            AsW + t * 16 * BK);
        }
        #pragma unroll
        for (int t = 0; t < 2; ++t)
            gload_lds16(B + (size_t)(colB0 + sRow + t * 16) * K + k0 + sCol,
                        BsW + t * 16 * BK);
        __syncthreads();

        bf16x8_t af[4], bfr[4];
        #pragma unroll
        for (int i = 0; i < 4; ++i)
            af[i] = *(const bf16x8_t*)&As[(wm + i * 16 + fr) * BK + kb];
        #pragma unroll
        for (int j = 0; j < 4; ++j)
            bfr[j] = *(const bf16x8_t*)&Bs[(wn + j * 16 + fr) * BK + kb];
        #pragma unroll
        for (int i = 0; i < 4; ++i)
            #pragma unroll
            for (int j = 0; j < 4; ++j)
                acc[i][j] = __builtin_amdgcn_mfma_f32_16x16x32_bf16(af[i], bfr[j], acc[i][j], 0, 0, 0);
    }

    // C/D layout: col = lane&15, row = (lane>>4)*4 + reg
    int cl = lane & 15;
    int rq = (lane >> 4) * 4;
    #pragma unroll
    for (int j = 0; j < 4; ++j) {
        int col = colB0 + wn + j * 16 + cl;
        float b = (col < NL) ? bias[col] : 0.f;
        #pragma unroll
        for (int i = 0; i < 4; ++i) {
            #pragma unroll
            for (int rr = 0; rr < 4; ++rr) {
                int row = rowA0 + wm + i * 16 + rq + rr;
                float v = acc[i][j][rr] + b;
                if constexpr (SIG) {
                    v = 1.f / (1.f + __expf(-v));
                    unsigned short o = (col < NL) ? f2bf(v) : (unsigned short)0;
                    ((unsigned short*)Cout)[(size_t)row * N + col] = o;
                } else {
                    ((float*)Cout)[(size_t)row * N + col] = v;
                }
            }
        }
    }
}

// one wave per target node: h2[n] = sum_{e: col==n} norm_e * cw * h[src_e] + h[n]
__global__ __launch_bounds__(256) void aggregate_k(
    const unsigned short* __restrict__ h, const int* __restrict__ colptr,
    const int* __restrict__ csr_src, const float* __restrict__ csr_nrm,
    const float* __restrict__ convw, unsigned short* __restrict__ h2)
{
    int lane = threadIdx.x & 63;
    int node = blockIdx.x * 4 + (threadIdx.x >> 6);
    float cw = convw[0];
    float acc[8] = {0.f, 0.f, 0.f, 0.f, 0.f, 0.f, 0.f, 0.f};
    int p0 = colptr[node], p1 = colptr[node + 1];
    int off = lane * 8;
    for (int i = p0; i < p1; ++i) {
        int r = csr_src[i];
        float w = csr_nrm[i] * cw;
        uint4 hv = *(const uint4*)(h + (size_t)r * EMBP + off);
        const unsigned short* hs = (const unsigned short*)&hv;
        #pragma unroll
        for (int j = 0; j < 8; ++j) acc[j] += w * bf2f(hs[j]);
    }
    uint4 hn = *(const uint4*)(h + (size_t)node * EMBP + off);
    const unsigned short* hs = (const unsigned short*)&hn;
    uint4 o;
    unsigned short ov[8];
    #pragma unroll
    for (int j = 0; j < 8; ++j) ov[j] = f2bf(acc[j] + bf2f(hs[j]));
    o.x = (unsigned)ov[0] | ((unsigned)ov[1] << 16);
    o.y = (unsigned)ov[2] | ((unsigned)ov[3] << 16);
    o.z = (unsigned)ov[4] | ((unsigned)ov[5] << 16);
    o.w = (unsigned)ov[6] | ((unsigned)ov[7] << 16);
    *(uint4*)(h2 + (size_t)node * EMBP + off) = o;
}

extern "C" void kernel_launch(void* const* d_in, const int* in_sizes, int n_in,
                              void* d_out, int out_size, void* d_ws, size_t ws_size,
                              hipStream_t stream) {
    const float* x = (const float*)d_in[0];
    const int* ei = (const int*)d_in[1];     // int32 [2,E] (harness converts integer inputs)
    const float* wenc = (const float*)d_in[2];
    const float* benc = (const float*)d_in[3];
    const float* wdec = (const float*)d_in[4];
    const float* bdec = (const float*)d_in[5];
    const float* convw = (const float*)d_in[6];
    float* out = (float*)d_out;

    char* ws = (char*)d_ws;
    size_t off = 0;
    auto alloc = [&](size_t bytes) -> void* {
        void* p = ws + off;
        off += (bytes + 255) & ~(size_t)255;
        return p;
    };
    unsigned short* wencb = (unsigned short*)alloc((size_t)EMBP * IN_SIZE * 2);
    unsigned short* wdecb = (unsigned short*)alloc((size_t)IN_SIZE * EMBP * 2);
    unsigned short* h     = (unsigned short*)alloc((size_t)N_NODES * EMBP * 2);
    unsigned short* h2    = (unsigned short*)alloc((size_t)N_NODES * EMBP * 2);
    int*   deg     = (int*)alloc(N_NODES * 4);    // deg & coldeg contiguous (zeroed together)
    int*   coldeg  = (int*)alloc(N_NODES * 4);
    float* dinv    = (float*)alloc(N_NODES * 4);
    int*   colptr  = (int*)alloc((N_NODES + 1) * 4);
    int*   cursor  = (int*)alloc(N_NODES * 4);
    int*   csr_src = (int*)alloc((size_t)NEDGE * 4);
    float* csr_nrm = (float*)alloc((size_t)NEDGE * 4);

    zero_i32<<<(2 * N_NODES) / 256, 256, 0, stream>>>(deg, 2 * N_NODES);
    hist_k<<<NEDGE / 256, 256, 0, stream>>>(ei, deg, coldeg);
    dinv_k<<<N_NODES / 256, 256, 0, stream>>>(deg, dinv);
    scan_k<<<1, 256, 0, stream>>>(coldeg, colptr, cursor);
    fill_k<<<NEDGE / 256, 256, 0, stream>>>(ei, dinv, cursor, csr_src, csr_nrm);
    cast_wenc_k<<<(EMBP * IN_SIZE) / 256, 256, 0, stream>>>(wenc, wencb);
    cast_wdec_k<<<(IN_SIZE * EMBP) / 256, 256, 0, stream>>>(wdec, wdecb);

    // encode: h = sigmoid(x @ wenc^T + benc)  [16384, 512(bf16, cols>=500 zeroed)]
    gemm_bt<true, true><<<dim3(N_NODES / 128, EMBP / 128), 256, 0, stream>>>(
        x, wencb, benc, h, N_NODES, EMBP, IN_SIZE, EMB);
    // GCN propagate + residual
    aggregate_k<<<N_NODES / 4, 256, 0, stream>>>(h, colptr, csr_src, csr_nrm, convw, h2);
    // decode: out = h2 @ wdec^T + bdec  [16384, 4096] fp32
    gemm_bt<false, false><<<dim3(N_NODES / 128, IN_SIZE / 128), 256, 0, stream>>>(
        h2, wdecb, bdec, out, N_NODES, IN_SIZE, EMBP, IN_SIZE);
}